// Round 2
// baseline (2064.521 us; speedup 1.0000x reference)
//
#include <hip/hip_runtime.h>

#define HH 64
#define WW 64
#define HO 62
#define WO 62
#define NV 8          // N_CONVS
#define NF 9          // features per pixel: silu + 8 spline bases
#define TILE_Y 8
#define IN_ROWS 10    // TILE_Y + 2

// block = 256 threads; grid = (B*C planes = 256, y-tiles = 8)
// Thread owns column tx (0..63, masked >=62) and rows ty, ty+4 of the tile.
__global__ __launch_bounds__(256, 4) void kan_conv_kernel(
    const float* __restrict__ x,     // (B,C,64,64)
    const float* __restrict__ grid,  // (9,12) rows identical, uniform knots
    const float* __restrict__ bw,    // (8,9)
    const float* __restrict__ sw,    // (8,9,8)
    const float* __restrict__ sc,    // (8,9)
    float* __restrict__ out)         // (B, C*8, 62, 62)
{
    __shared__ float feat[IN_ROWS * WW * NF];  // 10*64*9*4B = 22.5 KB
    __shared__ float wts[9 * NF * NV];         // 648 floats = 2.6 KB

    const int tid   = threadIdx.x;
    const int plane = blockIdx.x;              // b*C + c
    const int oy    = blockIdx.y * TILE_Y;

    // ---- fold weights into LDS: f==0 -> base_weight, f>=1 -> spline_weight*scaler
    for (int i = tid; i < 9 * NF * NV; i += 256) {
        const int v = i & 7;
        const int f = (i >> 3) % 9;
        const int k = i / 72;
        wts[i] = (f == 0) ? bw[v * 9 + k]
                          : sw[(v * 9 + k) * 8 + (f - 1)] * sc[v * 9 + k];
    }

    // uniform-grid parameters (wave-uniform scalar loads)
    const float g0    = grid[0];
    const float inv_h = 1.0f / (grid[1] - grid[0]);

    const float* xp = x + (size_t)plane * (HH * WW);

    // ---- stage 1: per-input-pixel features, NO per-thread arrays (spill fix)
    for (int idx = tid; idx < IN_ROWS * WW; idx += 256) {
        const int iy = idx >> 6;        // 0..9
        const int ix = idx & 63;        // 0..63
        const int gy = oy + iy;
        const float xv = (gy < HH) ? xp[gy * WW + ix] : 0.0f;

        // silu
        const float s = xv / (1.0f + __expf(-xv));

        // uniform cubic B-spline: interval j, local t in [0,1)
        const float u = (xv - g0) * inv_h;
        int j = (int)floorf(u);
        j = (j < 3) ? 3 : ((j > 7) ? 7 : j);
        const float t   = u - (float)j;
        const float omt = 1.0f - t;
        const float t2  = t * t;
        const float t3  = t2 * t;
        const float c6  = 1.0f / 6.0f;
        const float bA = omt * omt * omt * c6;                    // B_{j-3}
        const float bB = (3.0f * t3 - 6.0f * t2 + 4.0f) * c6;     // B_{j-2}
        const float bC = (-3.0f * t3 + 3.0f * t2 + 3.0f * t + 1.0f) * c6; // B_{j-1}
        const float bD = t3 * c6;                                 // B_j

        float* fp = &feat[idx * NF];
        fp[0] = s;
        #pragma unroll
        for (int m = 1; m <= 8; ++m) fp[m] = 0.0f;
        // basis i is feature f = 1+i; nonzero i = j-3..j  ->  f = j-2..j+1 (1..8)
        fp[j - 2] = bA;
        fp[j - 1] = bB;
        fp[j]     = bC;
        fp[j + 1] = bD;
    }
    __syncthreads();

    // ---- stage 2: 3x3 conv over 9 features -> 8 outputs, 2 pixels/thread
    const int tx = tid & 63;   // column
    const int ty = tid >> 6;   // 0..3 (rows ty, ty+4)
    if (tx >= WO) return;

    float acc[2][NV];
    #pragma unroll
    for (int p = 0; p < 2; ++p)
        #pragma unroll
        for (int v = 0; v < NV; ++v) acc[p][v] = 0.0f;

    #pragma unroll
    for (int ki = 0; ki < 3; ++ki) {
        #pragma unroll
        for (int kj = 0; kj < 3; ++kj) {
            const int k = ki * 3 + kj;
            #pragma unroll
            for (int f = 0; f < NF; ++f) {
                const float4 w0 = *reinterpret_cast<const float4*>(&wts[(k * NF + f) * NV]);
                const float4 w1 = *reinterpret_cast<const float4*>(&wts[(k * NF + f) * NV + 4]);
                #pragma unroll
                for (int p = 0; p < 2; ++p) {
                    const int iy = ty + 4 * p + ki;            // 0..9
                    const float fv = feat[((iy << 6) + tx + kj) * NF + f];
                    acc[p][0] += fv * w0.x;
                    acc[p][1] += fv * w0.y;
                    acc[p][2] += fv * w0.z;
                    acc[p][3] += fv * w0.w;
                    acc[p][4] += fv * w1.x;
                    acc[p][5] += fv * w1.y;
                    acc[p][6] += fv * w1.z;
                    acc[p][7] += fv * w1.w;
                }
            }
        }
    }

    // ---- store: out[((plane*8 + v)*HO + ho)*WO + wo]
    #pragma unroll
    for (int p = 0; p < 2; ++p) {
        const int ho = oy + ty + 4 * p;
        if (ho < HO) {
            #pragma unroll
            for (int v = 0; v < NV; ++v) {
                out[((size_t)(plane * NV + v) * HO + ho) * WO + tx] = acc[p][v];
            }
        }
    }
}

extern "C" void kernel_launch(void* const* d_in, const int* in_sizes, int n_in,
                              void* d_out, int out_size, void* d_ws, size_t ws_size,
                              hipStream_t stream) {
    const float* x    = (const float*)d_in[0];
    const float* grid = (const float*)d_in[1];
    const float* bw   = (const float*)d_in[2];
    const float* sw   = (const float*)d_in[3];
    const float* sc   = (const float*)d_in[4];
    float* out = (float*)d_out;

    dim3 grid_dim(256, 8);   // 256 (b,c) planes x 8 y-tiles
    kan_conv_kernel<<<grid_dim, 256, 0, stream>>>(x, grid, bw, sw, sc, out);
}

// Round 4
// 130.155 us; speedup vs baseline: 15.8620x; 15.8620x over previous
//
#include <hip/hip_runtime.h>

#define NV 8
#define HO 62
#define WO 62
#define N_UNITS 2048   // 256 planes x 8 row-chunks
#define N_BLOCKS 256

// Block = 512 threads = 8 waves. Wave w handles output conv v=w for a unit.
// Lane = column (0..63). Each unit = (plane, 8-row output chunk).
// No LDS, no barriers. Weights in registers (81 per thread, wave-uniform).
__global__ __launch_bounds__(512, 2) void kan_conv_rolling(
    const float* __restrict__ x,     // (256, 64, 64)
    const float* __restrict__ grid,  // (9, 12) rows identical, uniform
    const float* __restrict__ bw,    // (8, 9)
    const float* __restrict__ sw,    // (8, 9, 8)
    const float* __restrict__ sc,    // (8, 9)
    float* __restrict__ out)         // (256*8, 62, 62)
{
    const int lane = threadIdx.x & 63;
    const int v    = threadIdx.x >> 6;    // 0..7, wave-uniform

    // ---- fold weights into registers: w[ki][kj][f], f=0 silu, f=1..8 spline
    float w[3][3][9];
    #pragma unroll
    for (int ki = 0; ki < 3; ++ki) {
        #pragma unroll
        for (int kj = 0; kj < 3; ++kj) {
            const int kk = ki * 3 + kj;
            const float scv = sc[v * 9 + kk];
            w[ki][kj][0] = bw[v * 9 + kk];
            #pragma unroll
            for (int f = 1; f < 9; ++f)
                w[ki][kj][f] = sw[(v * 9 + kk) * 8 + (f - 1)] * scv;
        }
    }

    const float g0    = grid[0];
    const float inv_h = 1.0f / (grid[1] - grid[0]);

    for (int u = blockIdx.x; u < N_UNITS; u += N_BLOCKS) {
        const int plane = u >> 3;
        const int r0    = (u & 7) * 8;            // first output row of chunk
        const float* xp = x + (size_t)plane * 4096;
        float* op = out + (size_t)(plane * NV + v) * (HO * WO);

        float acc[3];
        acc[0] = acc[1] = acc[2] = 0.0f;

        // rolling over input rows r0..r0+9; all indices compile-time static
        #pragma unroll
        for (int k = 0; k < 10; ++k) {
            const int rr  = r0 + k;
            const int row = (rr < 64) ? rr : 63;   // clamp; clamped rows only
                                                   // feed masked output rows
            const float xv = xp[row * 64 + lane];

            // features: silu + uniform cubic B-spline (4 non-zero bases)
            const float s  = xv / (1.0f + __expf(-xv));
            const float uu = (xv - g0) * inv_h;
            int j = (int)floorf(uu);
            j = (j < 3) ? 3 : ((j > 7) ? 7 : j);
            const float t   = uu - (float)j;
            const float omt = 1.0f - t;
            const float t2  = t * t;
            const float t3  = t2 * t;
            const float c6  = 1.0f / 6.0f;
            const float bA  = omt * omt * omt * c6;
            const float bB  = (3.0f * t3 - 6.0f * t2 + 4.0f) * c6;
            const float bC  = (-3.0f * t3 + 3.0f * t2 + 3.0f * t + 1.0f) * c6;
            const float bD  = t3 * c6;

            float ff[9];
            ff[0] = s;
            #pragma unroll
            for (int f = 1; f < 9; ++f) {   // branchless select, no reg scatter
                const int d = j - (f - 1);  // basis i = f-1; d=j-i
                float val = 0.0f;
                val = (d == 3) ? bA : val;
                val = (d == 2) ? bB : val;
                val = (d == 1) ? bC : val;
                val = (d == 0) ? bD : val;
                ff[f] = val;
            }

            // slot k%3 starts a new output row (r0+k); zero it first
            acc[k % 3] = 0.0f;

            #pragma unroll
            for (int f = 0; f < 9; ++f) {
                const float v0 = ff[f];
                const float v1 = __shfl(v0, lane + 1, 64); // col c+1
                const float v2 = __shfl(v0, lane + 2, 64); // col c+2
                // input row rr serves output row rr-ki (slot (k-ki)%3)
                acc[k % 3] += v0 * w[0][0][f] + v1 * w[0][1][f] + v2 * w[0][2][f];
                if (k >= 1)
                    acc[(k + 2) % 3] += v0 * w[1][0][f] + v1 * w[1][1][f] + v2 * w[1][2][f];
                if (k >= 2)
                    acc[(k + 1) % 3] += v0 * w[2][0][f] + v1 * w[2][1][f] + v2 * w[2][2][f];
            }

            // output row r0+k-2 is complete (got its ki=2 taps)
            if (k >= 2) {
                const int ho = rr - 2;
                if (ho < HO && lane < WO)
                    op[ho * WO + lane] = acc[(k + 1) % 3];
            }
        }
    }
}

extern "C" void kernel_launch(void* const* d_in, const int* in_sizes, int n_in,
                              void* d_out, int out_size, void* d_ws, size_t ws_size,
                              hipStream_t stream) {
    const float* x    = (const float*)d_in[0];
    const float* grid = (const float*)d_in[1];
    const float* bw   = (const float*)d_in[2];
    const float* sw   = (const float*)d_in[3];
    const float* sc   = (const float*)d_in[4];
    float* out = (float*)d_out;

    kan_conv_rolling<<<N_BLOCKS, 512, 0, stream>>>(x, grid, bw, sw, sc, out);
}

// Round 5
// 96.149 us; speedup vs baseline: 21.4721x; 1.3537x over previous
//
#include <hip/hip_runtime.h>

#define NV 8
#define HO 62
#define WO 62

// 4096 blocks x 256 threads (4 waves). Block = (plane, row-chunk, v-half).
// Wave vl handles conv v = 4*half + vl. Lane = column (0..63).
// Sparse-spline: only 4 cubic bases are nonzero -> 4-weight LDS window
// keyed by knot interval j. ds_read_b128 16B-aligned; bank window
// 4*(j-3) mod 32 distinct per j (equal j -> broadcast) => conflict-free.
__global__ __launch_bounds__(256, 4) void kan_conv_sparse(
    const float* __restrict__ x,     // (256, 64, 64)
    const float* __restrict__ grid,  // (9, 12) rows identical, uniform
    const float* __restrict__ bw,    // (8, 9)
    const float* __restrict__ sw,    // (8, 9, 8)
    const float* __restrict__ sc,    // (8, 9)
    float* __restrict__ out)         // (256*8, 62, 62)
{
    __shared__ float wspl[4][5][9][4];   // [vl][j-3][tap][m] = 2.88 KB

    const int tid  = threadIdx.x;
    const int lane = tid & 63;
    const int vl   = tid >> 6;           // wave id 0..3

    const int item  = blockIdx.x;        // 0..4095
    const int plane = item >> 4;
    const int chunk = (item >> 1) & 7;
    const int half  = item & 1;
    const int v     = half * 4 + vl;

    // ---- fold spline weights into LDS windows (720 floats, 3 passes)
    for (int i = tid; i < 720; i += 256) {
        const int m  = i & 3;
        const int kk = (i >> 2) % 9;
        const int jj = (i / 36) % 5;
        const int wl = i / 180;
        const int wv = half * 4 + wl;
        wspl[wl][jj][kk][m] = sw[(wv * 9 + kk) * 8 + jj + m] * sc[wv * 9 + kk];
    }

    // silu weights in registers (wave-uniform)
    float wb[9];
    #pragma unroll
    for (int kk = 0; kk < 9; ++kk) wb[kk] = bw[v * 9 + kk];

    const float g0    = grid[0];
    const float inv_h = 1.0f / (grid[1] - grid[0]);

    __syncthreads();

    const int r0 = chunk * 8;
    const float* xp = x + (size_t)plane * 4096;
    float* op = out + (size_t)(plane * NV + v) * (HO * WO);

    float acc[3] = {0.0f, 0.0f, 0.0f};

    // rolling stencil over 10 input rows; all indexing compile-time static
    #pragma unroll
    for (int k = 0; k < 10; ++k) {
        const int rr  = r0 + k;
        const int row = (rr < 64) ? rr : 63;     // clamped rows feed masked outputs
        const float xv = xp[row * 64 + lane];

        // silu + uniform cubic B-spline (4 nonzero bases)
        const float s = xv / (1.0f + __expf(-xv));
        const float u = (xv - g0) * inv_h;
        int j = (int)floorf(u);
        j = (j < 3) ? 3 : ((j > 7) ? 7 : j);
        const float t   = u - (float)j;
        const float omt = 1.0f - t;
        const float t2  = t * t;
        const float t3  = t2 * t;
        const float c6  = 1.0f / 6.0f;
        const float bA  = omt * omt * omt * c6;
        const float bB  = (3.0f * t3 - 6.0f * t2 + 4.0f) * c6;
        const float bC  = (-3.0f * t3 + 3.0f * t2 + 3.0f * t + 1.0f) * c6;
        const float bD  = t3 * c6;

        // per-lane dot for each of the 9 taps (sparse: 5 FMA + 1 b128 each)
        float D[9];
        #pragma unroll
        for (int kk = 0; kk < 9; ++kk) {
            const float4 w4 = *reinterpret_cast<const float4*>(&wspl[vl][j - 3][kk][0]);
            D[kk] = fmaf(s, wb[kk],
                     fmaf(bA, w4.x, fmaf(bB, w4.y, fmaf(bC, w4.z, bD * w4.w))));
        }

        // cross-column gather (lane 63 wraps -> garbage, store-masked)
        const float d01 = __shfl(D[1], lane + 1, 64);
        const float d02 = __shfl(D[2], lane + 2, 64);
        const float d11 = __shfl(D[4], lane + 1, 64);
        const float d12 = __shfl(D[5], lane + 2, 64);
        const float d21 = __shfl(D[7], lane + 1, 64);
        const float d22 = __shfl(D[8], lane + 2, 64);

        acc[k % 3] = D[0] + d01 + d02;                       // ki=0 starts row rr
        if (k >= 1) acc[(k + 2) % 3] += D[3] + d11 + d12;    // ki=1 -> row rr-1
        if (k >= 2) {
            acc[(k + 1) % 3] += D[6] + d21 + d22;            // ki=2 -> row rr-2 done
            const int ho = rr - 2;
            if (ho < HO && lane < WO)
                op[ho * WO + lane] = acc[(k + 1) % 3];
        }
    }
}

extern "C" void kernel_launch(void* const* d_in, const int* in_sizes, int n_in,
                              void* d_out, int out_size, void* d_ws, size_t ws_size,
                              hipStream_t stream) {
    const float* x    = (const float*)d_in[0];
    const float* grid = (const float*)d_in[1];
    const float* bw   = (const float*)d_in[2];
    const float* sw   = (const float*)d_in[3];
    const float* sc   = (const float*)d_in[4];
    float* out = (float*)d_out;

    kan_conv_sparse<<<4096, 256, 0, stream>>>(x, grid, bw, sw, sc, out);
}

// Round 6
// 94.183 us; speedup vs baseline: 21.9202x; 1.0209x over previous
//
#include <hip/hip_runtime.h>

typedef _Float16 f16;
typedef _Float16 f16x8 __attribute__((ext_vector_type(8)));
typedef float    f32x4 __attribute__((ext_vector_type(4)));

#define HO 62
#define WO 62

// Block = 512 thr (8 waves), grid = 256 planes x 4 row-chunks (r0 in {0,16,32,46}).
// Stage 1: dense f16 feature map in LDS: per input pixel 16 slots
//   (slot0 = silu, slots1..8 = cubic B-spline bases, rest zero), stored as two
//   8-f16 chunks: feat[row*1024 + khalf*512 + col*8 + (slot&7)].
// Stage 2: per 16-output-col x 8-v tile: 6 MFMAs f32_16x16x32_f16.
//   A[m][k]: m = output col, k = (colOff = k>>4 within pair, slot = k&15).
//   B[k][n]: n<8 -> v=n; rows with kj>2 or slot>8 are ZERO (pads).
__global__ __launch_bounds__(512, 4) void kan_conv_mfma(
    const float* __restrict__ x,     // (256, 64, 64)
    const float* __restrict__ grid,  // (9, 12) uniform knots
    const float* __restrict__ bw,    // (8, 9)
    const float* __restrict__ sw,    // (8, 9, 8)
    const float* __restrict__ sc,    // (8, 9)
    float* __restrict__ out)         // (256*8, 62, 62)
{
    __shared__ __align__(16) f16 feat[19456];   // 38912 B (18 rows + zero tail)

    const int tid  = threadIdx.x;
    const int lane = tid & 63;
    const int w    = tid >> 6;

    const int bx    = blockIdx.x;
    const int plane = bx >> 2;
    const int chunk = bx & 3;
    const int r0    = (chunk < 3) ? chunk * 16 : 46;   // rows r0..r0+17 <= 63

    // ---- constant B fragments in registers: lane holds B[k=(l>>4)*8+e][n=l&15]
    const int nn = lane & 15;
    const int kb = lane >> 4;
    f16x8 bfrag[3][2];
    #pragma unroll
    for (int ki = 0; ki < 3; ++ki) {
        #pragma unroll
        for (int kjp = 0; kjp < 2; ++kjp) {
            f16x8 bf;
            #pragma unroll
            for (int e = 0; e < 8; ++e) {
                const int k    = kb * 8 + e;
                const int kj   = kjp * 2 + (k >> 4);
                const int slot = k & 15;
                float wv = 0.0f;
                if (nn < 8 && kj < 3 && slot < 9) {
                    const int kk = ki * 3 + kj;
                    wv = (slot == 0) ? bw[nn * 9 + kk]
                                     : sw[(nn * 9 + kk) * 8 + (slot - 1)] * sc[nn * 9 + kk];
                }
                bf[e] = (f16)wv;
            }
            bfrag[ki][kjp] = bf;
        }
    }

    // ---- stage 1: feature map (silu + uniform cubic B-spline, 4 nonzero bases)
    const float g0    = grid[0];
    const float inv_h = 1.0f / (grid[1] - grid[0]);
    const float* xp   = x + (size_t)plane * 4096;

    for (int idx = tid; idx < 18 * 64; idx += 512) {
        const int row = idx >> 6;
        const int col = idx & 63;
        const float xv = xp[(r0 + row) * 64 + col];

        const float s = xv / (1.0f + __expf(-xv));
        const float u = (xv - g0) * inv_h;
        int j = (int)floorf(u);
        j = (j < 3) ? 3 : ((j > 7) ? 7 : j);
        const float t   = u - (float)j;
        const float omt = 1.0f - t;
        const float t2  = t * t;
        const float t3  = t2 * t;
        const float c6  = 1.0f / 6.0f;
        float bv[4];
        bv[0] = omt * omt * omt * c6;                               // slot j-2
        bv[1] = (3.0f * t3 - 6.0f * t2 + 4.0f) * c6;                // slot j-1
        bv[2] = (-3.0f * t3 + 3.0f * t2 + 3.0f * t + 1.0f) * c6;    // slot j
        bv[3] = t3 * c6;                                            // slot j+1

        const int base0 = row * 1024 + col * 8;
        f16x8 z0 = {(f16)s, (f16)0.f, (f16)0.f, (f16)0.f,
                    (f16)0.f, (f16)0.f, (f16)0.f, (f16)0.f};
        f16x8 z1 = {(f16)0.f, (f16)0.f, (f16)0.f, (f16)0.f,
                    (f16)0.f, (f16)0.f, (f16)0.f, (f16)0.f};
        *(f16x8*)&feat[base0]       = z0;   // slots 0-7 (slot0 = silu)
        *(f16x8*)&feat[base0 + 512] = z1;   // slots 8-15 all zero
        #pragma unroll
        for (int m = 0; m < 4; ++m) {
            const int slot = j - 2 + m;     // 1..8
            feat[row * 1024 + (slot >> 3) * 512 + col * 8 + (slot & 7)] = (f16)bv[m];
        }
    }
    // zero the tail region so dead A-reads (B-row = 0) never hit NaN garbage
    for (int idx = tid; idx < 128; idx += 512) {
        f16x8 z = {(f16)0.f, (f16)0.f, (f16)0.f, (f16)0.f,
                   (f16)0.f, (f16)0.f, (f16)0.f, (f16)0.f};
        *(f16x8*)&feat[18432 + idx * 8] = z;
    }
    __syncthreads();

    // ---- stage 2: MFMA. 64 units = 16 out-rows x 4 col-tiles; 8 per wave.
    const int mI    = lane & 15;    // A row = output col within tile
    const int khalf = kb & 1;       // slot half
    const int cAdd  = kb >> 1;      // col within k-span pair

    for (int u = w; u < 64; u += 8) {
        const int ro = u >> 2;
        const int c0 = (u & 3) * 16;          // {0,16,32,48}
        f32x4 acc = {0.f, 0.f, 0.f, 0.f};
        #pragma unroll
        for (int ki = 0; ki < 3; ++ki) {
            #pragma unroll
            for (int kjp = 0; kjp < 2; ++kjp) {
                const int col = c0 + mI + kjp * 2 + cAdd;
                const f16x8 a = *(const f16x8*)&feat[(ro + ki) * 1024 + khalf * 512 + col * 8];
                acc = __builtin_amdgcn_mfma_f32_16x16x32_f16(a, bfrag[ki][kjp], acc, 0, 0, 0);
            }
        }
        // C: lane holds D[row = kb*4+i][col = nn]; row = out col, col = v
        if (nn < 8) {
            const int rowg = r0 + ro;                 // always < 62
            const int colb = c0 + kb * 4;
            float* po = out + ((size_t)(plane * 8 + nn) * (HO * WO)) + rowg * WO + colb;
            if (c0 < 48) {                            // 8B-aligned fast path
                float2 lo = {acc[0], acc[1]};
                float2 hi = {acc[2], acc[3]};
                *(float2*)po       = lo;
                *(float2*)(po + 2) = hi;
            } else {
                #pragma unroll
                for (int i = 0; i < 4; ++i)
                    if (colb + i < WO) po[i] = acc[i];
            }
        }
    }
}

extern "C" void kernel_launch(void* const* d_in, const int* in_sizes, int n_in,
                              void* d_out, int out_size, void* d_ws, size_t ws_size,
                              hipStream_t stream) {
    const float* x    = (const float*)d_in[0];
    const float* grid = (const float*)d_in[1];
    const float* bw   = (const float*)d_in[2];
    const float* sw   = (const float*)d_in[3];
    const float* sc   = (const float*)d_in[4];
    float* out = (float*)d_out;

    kan_conv_mfma<<<1024, 512, 0, stream>>>(x, grid, bw, sw, sc, out);
}